// Round 20
// baseline (132.688 us; speedup 1.0000x reference)
//
#include <hip/hip_runtime.h>

// MHA forward: S=2048, B=4, E=512, H=8, D=64.
// qkv_kernel -> maskprep_kernel -> attn_kernel -> oproj_kernel.
// R20 = R19 + attn K/V staging via __builtin_amdgcn_global_load_lds(16B):
// LDS dest is linear per-lane (wave base + lane*16); the XOR swizzle moves
// to the GLOBAL source address (unit (l&7)^(l>>3)) so the existing swizzled
// reader offsets (fof) are unchanged (m97/m173 pattern). Removes the 16
// staging VGPRs, all ds_writes and staging address VALU; loads overlap
// COMPUTE and drain at the per-iter barrier.

#define L2E 1.44269504088896340736f

#if defined(__has_builtin)
#  if __has_builtin(__builtin_amdgcn_exp2f)
#    define EXP2(x) __builtin_amdgcn_exp2f(x)
#  else
#    define EXP2(x) exp2f(x)
#  endif
#else
#  define EXP2(x) exp2f(x)
#endif

typedef __attribute__((ext_vector_type(8))) __bf16 bf16x8;
typedef __attribute__((ext_vector_type(4))) float f32x4;
typedef __attribute__((ext_vector_type(16))) float f32x16;

static __device__ __forceinline__ unsigned pk2(float a, float b) {
    union { unsigned u; __bf16 h[2]; } cv;
    cv.h[0] = (__bf16)a; cv.h[1] = (__bf16)b;
    return cv.u;
}

static __device__ __forceinline__ unsigned short f2bf(float f) {
    union { unsigned short s; __bf16 h; } cv;
    cv.h = (__bf16)f;
    return cv.s;
}

static __device__ __forceinline__ float bflo(unsigned u) {
    union { unsigned u; float f; } cv; cv.u = u << 16; return cv.f;
}
static __device__ __forceinline__ float bfhi(unsigned u) {
    union { unsigned u; float f; } cv; cv.u = u & 0xFFFF0000u; return cv.f;
}

// ---------------------------------------------------------------------------
// Kernel 0: QKV projection. 1D grid 768, XCD-swizzled decode (R18, proven):
//   c=g&7 (XCD), i=g>>3, x=i&3 (n-tile), p=(i>>2)*8+c, y=p&63, z=p>>6.
//   z=0 -> Qp[bh][s][d] scaled by L2E/8, z=1 -> Kp, z=2 -> Vt[bh][d][s].
// ---------------------------------------------------------------------------
__global__ __launch_bounds__(256) void qkv_kernel(
    const float* __restrict__ Xq, const float* __restrict__ Xk,
    const float* __restrict__ Xv, const float* __restrict__ W,
    const float* __restrict__ bias,
    unsigned short* __restrict__ Qp, unsigned short* __restrict__ Kp,
    unsigned short* __restrict__ Vt)
{
    __shared__ unsigned short lA[128][40];
    __shared__ unsigned short lB[128][40];

    const int g = blockIdx.x;
    const int c = g & 7, i = g >> 3;
    const int x = i & 3;
    const int p = (i >> 2) * 8 + c;     // panel 0..191
    const int y = p & 63;
    const int z = p >> 6;

    const float* X  = (z == 0) ? Xq : (z == 1) ? Xk : Xv;
    const float* Wz = W + (size_t)z * 512 * 512;
    const int rb = y * 128;
    const int nb = x * 128;
    const int tid  = threadIdx.x;
    const int lane = tid & 63, wave = tid >> 6;
    const int wr = wave >> 1, wc = wave & 1;
    const int lq = lane & 15, lg = lane >> 4;

    f32x4 acc[4][4];
#pragma unroll
    for (int ii = 0; ii < 4; ++ii)
#pragma unroll
        for (int j = 0; j < 4; ++j) acc[ii][j] = (f32x4){0.f, 0.f, 0.f, 0.f};

    const int srow = tid >> 1;
    const int scol = (tid & 1) * 16;

    for (int kt = 0; kt < 16; ++kt) {
        const int k0 = kt * 32;
        if (kt) __syncthreads();
        {
            const float* gp = X + (size_t)(rb + srow) * 512 + k0 + scol;
            float4 x0 = *(const float4*)(gp + 0);
            float4 x1 = *(const float4*)(gp + 4);
            float4 x2 = *(const float4*)(gp + 8);
            float4 x3 = *(const float4*)(gp + 12);
            uint4 w0, w1;
            w0.x = pk2(x0.x, x0.y); w0.y = pk2(x0.z, x0.w);
            w0.z = pk2(x1.x, x1.y); w0.w = pk2(x1.z, x1.w);
            w1.x = pk2(x2.x, x2.y); w1.y = pk2(x2.z, x2.w);
            w1.z = pk2(x3.x, x3.y); w1.w = pk2(x3.z, x3.w);
            *(uint4*)&lA[srow][scol] = w0;
            *(uint4*)&lA[srow][scol + 8] = w1;
        }
        {
            const float* gp = Wz + (size_t)(nb + srow) * 512 + k0 + scol;
            float4 x0 = *(const float4*)(gp + 0);
            float4 x1 = *(const float4*)(gp + 4);
            float4 x2 = *(const float4*)(gp + 8);
            float4 x3 = *(const float4*)(gp + 12);
            uint4 w0, w1;
            w0.x = pk2(x0.x, x0.y); w0.y = pk2(x0.z, x0.w);
            w0.z = pk2(x1.x, x1.y); w0.w = pk2(x1.z, x1.w);
            w1.x = pk2(x2.x, x2.y); w1.y = pk2(x2.z, x2.w);
            w1.z = pk2(x3.x, x3.y); w1.w = pk2(x3.z, x3.w);
            *(uint4*)&lB[srow][scol] = w0;
            *(uint4*)&lB[srow][scol + 8] = w1;
        }
        __syncthreads();

        bf16x8 af[4], bf[4];
#pragma unroll
        for (int mi = 0; mi < 4; ++mi)
            af[mi] = *(const bf16x8*)&lA[wr * 64 + mi * 16 + lq][lg * 8];
#pragma unroll
        for (int ni = 0; ni < 4; ++ni)
            bf[ni] = *(const bf16x8*)&lB[wc * 64 + ni * 16 + lq][lg * 8];
#pragma unroll
        for (int mi = 0; mi < 4; ++mi)
#pragma unroll
            for (int ni = 0; ni < 4; ++ni)
                acc[mi][ni] = __builtin_amdgcn_mfma_f32_16x16x32_bf16(
                    af[mi], bf[ni], acc[mi][ni], 0, 0, 0);
    }

    const float* bz = bias + z * 512;
#pragma unroll
    for (int ni = 0; ni < 4; ++ni) {
        const int n = nb + wc * 64 + ni * 16 + lq;
        const float bv = bz[n];
        const int h = n >> 6, d = n & 63;
#pragma unroll
        for (int mi = 0; mi < 4; ++mi) {
#pragma unroll
            for (int r = 0; r < 4; ++r) {
                const int t = rb + wr * 64 + mi * 16 + lg * 4 + r;
                float v = acc[mi][ni][r] + bv;
                const int s = t >> 2, b = t & 3;
                if (z == 0) {
                    v *= 0.125f * L2E;
                    Qp[((size_t)(b * 8 + h) * 2048 + s) * 64 + d] = f2bf(v);
                } else if (z == 1) {
                    Kp[((size_t)(b * 8 + h) * 2048 + s) * 64 + d] = f2bf(v);
                } else {
                    Vt[((size_t)(b * 8 + h) * 64 + d) * 2048 + s] = f2bf(v);
                }
            }
        }
    }
}

// ---------------------------------------------------------------------------
// Kernel 0.5: mask -> bf16 fragment layout via LDS transpose (R12 verbatim).
// Mf[(bq*64+kt)*1024 + lane*16 + jj] =
//   mask[b][qt*32+(lane&31)][kt*32 + (jj&3)+8*(jj>>2)+4*(lane>>5)] * L2E
// ---------------------------------------------------------------------------
__global__ __launch_bounds__(256) void maskprep_kernel(
    const float* __restrict__ mask, unsigned short* __restrict__ Mf)
{
    __shared__ float lT[32][261];
    const int tid = threadIdx.x;
    const int bq = blockIdx.y;                  // b*64 + qt
    const int kx = blockIdx.x;                  // k-chunk of 256
    const float* base = mask + ((size_t)(bq >> 6) * 2048 + (bq & 63) * 32) * 2048
                        + (size_t)kx * 256;

    const int r = tid >> 3, ci = tid & 7;
    const float* rp = base + (size_t)r * 2048;
#pragma unroll
    for (int j = 0; j < 8; ++j) {
        const int cidx = (ci + j * 8) * 4;
        float4 v = *(const float4*)(rp + cidx);
        lT[r][cidx + 0] = v.x * L2E;
        lT[r][cidx + 1] = v.y * L2E;
        lT[r][cidx + 2] = v.z * L2E;
        lT[r][cidx + 3] = v.w * L2E;
    }
    __syncthreads();

    const int w = tid >> 6, lane = tid & 63;
    const int lc = lane & 31, hi = lane >> 5;
#pragma unroll
    for (int t = 0; t < 2; ++t) {
        const int ktl = w * 2 + t;
        float pv[16];
#pragma unroll
        for (int jj = 0; jj < 16; ++jj)
            pv[jj] = lT[lc][ktl * 32 + (jj & 3) + 8 * (jj >> 2) + 4 * hi];
        unsigned short* dst = Mf + ((size_t)bq * 64 + kx * 8 + ktl) * 1024 + lane * 16;
        *(uint4*)(dst) = make_uint4(pk2(pv[0], pv[1]), pk2(pv[2], pv[3]),
                                    pk2(pv[4], pv[5]), pk2(pv[6], pv[7]));
        *(uint4*)(dst + 8) = make_uint4(pk2(pv[8], pv[9]),  pk2(pv[10], pv[11]),
                                        pk2(pv[12], pv[13]), pk2(pv[14], pv[15]));
    }
}

// ---------------------------------------------------------------------------
// Kernel 1: flash attention. grid (16 q-tiles, 32 bh), no swizzle (R19).
// 32x32x16 MFMA, swapped QK^T, mask C-init from Mf, EXP2 hw intrinsic.
// K/V staging via global_load_lds(16B): LDS linear per-lane, XOR swizzle
// applied to the GLOBAL source unit ((l&7)^(l>>3)); readers (fof) unchanged.
// Dbuf LDS, 1 barrier/tile; loads for tile t+1 fly during COMPUTE of t.
// ---------------------------------------------------------------------------
#define SWAP32(a, b) asm("v_permlane32_swap_b32 %0, %1" : "+v"(a), "+v"(b))

#define GLL(l, gptr) __builtin_amdgcn_global_load_lds(                         \
    (const __attribute__((address_space(1))) void*)(gptr),                     \
    (__attribute__((address_space(3))) void*)(l), 16, 0, 0)

#define COMPUTE(KC, VC, M) do {                                                \
    bf16x8 pf[4];                                                              \
    _Pragma("unroll")                                                          \
    for (int kblk = 0; kblk < 2; ++kblk) {                                     \
        f32x16 z;                                                              \
        {                                                                      \
            const uint4 m0 = M[kblk][0], m1 = M[kblk][1];                      \
            z[0]  = bflo(m0.x); z[1]  = bfhi(m0.x);                            \
            z[2]  = bflo(m0.y); z[3]  = bfhi(m0.y);                            \
            z[4]  = bflo(m0.z); z[5]  = bfhi(m0.z);                            \
            z[6]  = bflo(m0.w); z[7]  = bfhi(m0.w);                            \
            z[8]  = bflo(m1.x); z[9]  = bfhi(m1.x);                            \
            z[10] = bflo(m1.y); z[11] = bfhi(m1.y);                            \
            z[12] = bflo(m1.z); z[13] = bfhi(m1.z);                            \
            z[14] = bflo(m1.w); z[15] = bfhi(m1.w);                            \
        }                                                                      \
        __builtin_amdgcn_s_setprio(1);                                         \
        _Pragma("unroll")                                                      \
        for (int s = 0; s < 4; ++s) {                                          \
            bf16x8 kf = *(const bf16x8*)((KC) + fof[kblk][s]);                 \
            z = __builtin_amdgcn_mfma_f32_32x32x16_bf16(kf, qf[s], z, 0,0,0);  \
        }                                                                      \
        __builtin_amdgcn_s_setprio(0);                                         \
        float p[16];                                                           \
        _Pragma("unroll")                                                      \
        for (int ii = 0; ii < 16; ++ii) p[ii] = EXP2(z[ii]);                   \
        lsum += (((p[0]+p[1])+(p[2]+p[3])) + ((p[4]+p[5])+(p[6]+p[7])))        \
              + (((p[8]+p[9])+(p[10]+p[11])) + ((p[12]+p[13])+(p[14]+p[15]))); \
        unsigned a0 = pk2(p[0], p[1]),   b0 = pk2(p[4], p[5]);                 \
        unsigned a1 = pk2(p[2], p[3]),   b1 = pk2(p[6], p[7]);                 \
        SWAP32(a0, b0); SWAP32(a1, b1);                                        \
        union { unsigned w[4]; bf16x8 v; } u0;                                 \
        u0.w[0] = a0; u0.w[1] = a1; u0.w[2] = b0; u0.w[3] = b1;                \
        pf[kblk*2] = u0.v;                                                     \
        unsigned c0 = pk2(p[8], p[9]),   d0 = pk2(p[12], p[13]);               \
        unsigned c1 = pk2(p[10], p[11]), d1 = pk2(p[14], p[15]);               \
        SWAP32(c0, d0); SWAP32(c1, d1);                                        \
        union { unsigned w[4]; bf16x8 v; } u1;                                 \
        u1.w[0] = c0; u1.w[1] = c1; u1.w[2] = d0; u1.w[3] = d1;                \
        pf[kblk*2+1] = u1.v;                                                   \
    }                                                                          \
    __builtin_amdgcn_s_setprio(1);                                             \
    _Pragma("unroll")                                                          \
    for (int s = 0; s < 4; ++s) {                                              \
        bf16x8 vf0 = *(const bf16x8*)((VC) + fof[0][s]);                       \
        o0 = __builtin_amdgcn_mfma_f32_32x32x16_bf16(vf0, pf[s], o0, 0,0,0);   \
        bf16x8 vf1 = *(const bf16x8*)((VC) + fof[1][s]);                       \
        o1 = __builtin_amdgcn_mfma_f32_32x32x16_bf16(vf1, pf[s], o1, 0,0,0);   \
    }                                                                          \
    __builtin_amdgcn_s_setprio(0);                                             \
} while (0)

// per-wave: 4 direct-to-LDS loads (1KB each) cover this wave's 16 K-rows and
// 16 V-rows of the 64x64 tile; pointers advance one kv-tile per call.
#define STAGE(BUF) do {                                                        \
    GLL(&lK[BUF][w16][0],     pgK0);                                           \
    GLL(&lK[BUF][w16 + 8][0], pgK0 + 512);                                     \
    GLL(&lV[BUF][w16][0],     pgV0);                                           \
    GLL(&lV[BUF][w16 + 8][0], pgV0 + 16384);                                   \
    pgK0 += 4096; pgV0 += 64;                                                  \
} while (0)

#define LOADM(MD) do {                                                         \
    MD[0][0] = *(const uint4*)(pmf);                                           \
    MD[0][1] = *(const uint4*)(pmf + 8);                                       \
    MD[1][0] = *(const uint4*)(pmf + 1024);                                    \
    MD[1][1] = *(const uint4*)(pmf + 1032);                                    \
    pmf += 2048;                                                               \
} while (0)

__global__ __launch_bounds__(256, 2) void attn_kernel(
    const unsigned short* __restrict__ Qp, const unsigned short* __restrict__ Kp,
    const unsigned short* __restrict__ Vt, const unsigned short* __restrict__ Mf,
    unsigned short* __restrict__ AO)
{
    __shared__ unsigned short lK[2][64][64];   // [buf][k][d], swizzled 16B units
    __shared__ unsigned short lV[2][64][64];   // [buf][d][k], same swizzle

    const int bh = blockIdx.y;
    const int b = bh >> 3, h = bh & 7;
    const int qb = blockIdx.x * 128;
    const int tid  = threadIdx.x;
    const int lane = tid & 63, wave = tid >> 6;
    const int lc = lane & 31, hi = lane >> 5;
    const int qg = qb + wave * 32 + lc;
    const int w16 = wave * 16;

    bf16x8 qf[4];
    {
        const unsigned short* qp = Qp + ((size_t)bh * 2048 + qg) * 64 + hi * 8;
#pragma unroll
        for (int s = 0; s < 4; ++s)
            qf[s] = *(const bf16x8*)(qp + s * 16);
    }

    f32x16 o0, o1;
#pragma unroll
    for (int ii = 0; ii < 16; ++ii) { o0[ii] = 0.f; o1[ii] = 0.f; }
    float lsum = 0.f;

    int fof[2][4];
#pragma unroll
    for (int blk = 0; blk < 2; ++blk)
#pragma unroll
        for (int s = 0; s < 4; ++s)
            fof[blk][s] = (blk * 32 + lc) * 128 +
                          ((((s << 1) | hi) ^ (lane & 7)) * 16);

    const char* lK0c = (const char*)&lK[0][0][0];
    const char* lK1c = (const char*)&lK[1][0][0];
    const char* lV0c = (const char*)&lV[0][0][0];
    const char* lV1c = (const char*)&lV[1][0][0];

    // global_load_lds source: lane l covers LDS (row rK0 + 8j, unit l&7);
    // the swizzled global unit is (l&7)^(l>>3) (row&7 == l>>3).
    const int rK0 = w16 + (lane >> 3);
    const int su  = (lane & 7) ^ (lane >> 3);
    const unsigned short* pgK0 = Kp + (size_t)bh * 131072 + (size_t)rK0 * 64 + su * 8;
    const unsigned short* pgV0 = Vt + (size_t)bh * 131072 + (size_t)rK0 * 2048 + su * 8;
    const unsigned short* pmf = Mf +
        ((size_t)(b * 64 + (qb >> 5) + wave) * 64) * 1024 + lane * 16;

    uint4 mA[2][2], mB[2][2];

    STAGE(0);
    LOADM(mA);
    __syncthreads();

    for (int kb2 = 0; kb2 < 16; ++kb2) {
        // even half: stage tile kb+1 -> LDS[1], compute LDS[0]/mA
        {
            STAGE(1);
            LOADM(mB);
            COMPUTE(lK0c, lV0c, mA);
            __syncthreads();
        }
        // odd half: stage tile kb+1 -> LDS[0] (if any), compute LDS[1]/mB
        {
            if (kb2 < 15) {
                STAGE(0);
                LOADM(mA);
            }
            COMPUTE(lK1c, lV1c, mB);
            if (kb2 < 15) __syncthreads();
        }
    }

    // halves (lane, lane^32) hold disjoint k partials for q=lc
    lsum += __shfl_xor(lsum, 32);
    const float inv = 1.0f / lsum;

    unsigned short* ao = AO + ((size_t)qg * 4 + b) * 512 + h * 64;
#pragma unroll
    for (int gq = 0; gq < 4; ++gq) {
        const int d0 = gq * 8 + hi * 4;
        *(uint2*)(ao + d0) =
            make_uint2(pk2(o0[4*gq+0] * inv, o0[4*gq+1] * inv),
                       pk2(o0[4*gq+2] * inv, o0[4*gq+3] * inv));
        *(uint2*)(ao + 32 + d0) =
            make_uint2(pk2(o1[4*gq+0] * inv, o1[4*gq+1] * inv),
                       pk2(o1[4*gq+2] * inv, o1[4*gq+3] * inv));
    }
}

// ---------------------------------------------------------------------------
// Kernel 2: output projection. 1D grid 256, XCD-swizzled (R18):
//   c=g&7, i=g>>3, x=i&3 (n-tile), y=(i>>2)*8+c (m-tile 0..63).
// ---------------------------------------------------------------------------
__global__ __launch_bounds__(256) void oproj_kernel(
    const unsigned short* __restrict__ A, const float* __restrict__ W,
    const float* __restrict__ bias, float* __restrict__ out)
{
    __shared__ unsigned short lA[128][40];
    __shared__ unsigned short lB[128][40];

    const int g = blockIdx.x;
    const int c = g & 7, i = g >> 3;
    const int rb = ((i >> 2) * 8 + c) * 128;
    const int nb = (i & 3) * 128;
    const int tid  = threadIdx.x;
    const int lane = tid & 63, wave = tid >> 6;
    const int wr = wave >> 1, wc = wave & 1;
    const int lq = lane & 15, lg = lane >> 4;

    f32x4 acc[4][4];
#pragma unroll
    for (int ii = 0; ii < 4; ++ii)
#pragma unroll
        for (int j = 0; j < 4; ++j) acc[ii][j] = (f32x4){0.f, 0.f, 0.f, 0.f};

    const int srow = tid >> 1;
    const int scol = (tid & 1) * 16;

    for (int kt = 0; kt < 16; ++kt) {
        const int k0 = kt * 32;
        if (kt) __syncthreads();
        {
            const unsigned short* gp = A + (size_t)(rb + srow) * 512 + k0 + scol;
            *(uint4*)&lA[srow][scol]     = *(const uint4*)gp;
            *(uint4*)&lA[srow][scol + 8] = *(const uint4*)(gp + 8);
        }
        {
            const float* gp = W + (size_t)(nb + srow) * 512 + k0 + scol;
            float4 x0 = *(const float4*)(gp + 0);
            float4 x1 = *(const float4*)(gp + 4);
            float4 x2 = *(const float4*)(gp + 8);
            float4 x3 = *(const float4*)(gp + 12);
            uint4 w0, w1;
            w0.x = pk2(x0.x, x0.y); w0.y = pk2(x0.z, x0.w);
            w0.z = pk2(x1.x, x1.y); w0.w = pk2(x1.z, x1.w);
            w1.x = pk2(x2.x, x2.y); w1.y = pk2(x2.z, x2.w);
            w1.z = pk2(x3.x, x3.y); w1.w = pk2(x3.z, x3.w);
            *(uint4*)&lB[srow][scol] = w0;
            *(uint4*)&lB[srow][scol + 8] = w1;
        }
        __syncthreads();

        bf16x8 af[4], bfr[4];
#pragma unroll
        for (int mi = 0; mi < 4; ++mi)
            af[mi] = *(const bf16x8*)&lA[wr * 64 + mi * 16 + lq][lg * 8];
#pragma unroll
        for (int ni = 0; ni < 4; ++ni)
            bfr[ni] = *(const bf16x8*)&lB[wc * 64 + ni * 16 + lq][lg * 8];
#pragma unroll
        for (int mi = 0; mi < 4; ++mi)
#pragma unroll
            for (int ni = 0; ni < 4; ++ni)
                acc[mi][ni] = __builtin_amdgcn_mfma_f32_16x16x32_bf16(
                    af[mi], bfr[ni], acc[mi][ni], 0, 0, 0);
    }

#pragma unroll
    for (int ni = 0; ni < 4; ++ni) {
        const int n = nb + wc * 64 + ni * 16 + lq;
        const float bv = bias[n];
#pragma unroll
        for (int mi = 0; mi < 4; ++mi) {
#pragma unroll
            for (int r = 0; r < 4; ++r) {
                const int t = rb + wr * 64 + mi * 16 + lg * 4 + r;
                out[(size_t)t * 512 + n] = acc[mi][ni][r] + bv;
            }
        }
    }
}

extern "C" void kernel_launch(void* const* d_in, const int* in_sizes, int n_in,
                              void* d_out, int out_size, void* d_ws, size_t ws_size,
                              hipStream_t stream)
{
    (void)in_sizes; (void)n_in; (void)out_size; (void)ws_size;
    const float* query = (const float*)d_in[0];
    const float* key   = (const float*)d_in[1];
    const float* value = (const float*)d_in[2];
    const float* mask  = (const float*)d_in[3];
    const float* w_in  = (const float*)d_in[4];
    const float* b_in  = (const float*)d_in[5];
    const float* w_out = (const float*)d_in[6];
    const float* b_out = (const float*)d_in[7];
    float* out = (float*)d_out;

    char* ws = (char*)d_ws;
    const size_t MB = 1024 * 1024;
    unsigned short* Qp = (unsigned short*)(ws);            // [32][2048][64] bf16, 8 MB
    unsigned short* Kp = (unsigned short*)(ws + 8 * MB);   // 8 MB
    unsigned short* Vt = (unsigned short*)(ws + 16 * MB);  // [32][64][2048], 8 MB
    unsigned short* AO = (unsigned short*)(ws + 24 * MB);  // [8192][512] bf16, 8 MB
    unsigned short* Mf = (unsigned short*)(ws + 32 * MB);  // mask fragments, 32 MB

    qkv_kernel<<<dim3(768), 256, 0, stream>>>(query, key, value, w_in, b_in,
                                              Qp, Kp, Vt);
    maskprep_kernel<<<dim3(8, 256), 256, 0, stream>>>(mask, Mf);
    attn_kernel<<<dim3(16, 32), 256, 0, stream>>>(Qp, Kp, Vt, Mf, AO);
    oproj_kernel<<<dim3(256), 256, 0, stream>>>(AO, w_out, b_out, out);
}

// Round 21
// 131.006 us; speedup vs baseline: 1.0128x; 1.0128x over previous
//
#include <hip/hip_runtime.h>

// MHA forward: S=2048, B=4, E=512, H=8, D=64.
// qkv_kernel -> maskprep_kernel -> attn_kernel -> oproj_kernel.
// R21 = R19 with attn blocks widened to 256 q-rows (512 thr / 8 waves x 32q,
// grid (8,32) = 256 blocks = 1/CU): attn is L2/L3-fabric BW-bound
// (~520MB stream: Mf 256 + K/V 256); sharing one K/V stream across 8 waves
// halves K/V traffic (256->128MB). Per-wave program identical to R19
// (COMPUTE, Mf indexing, epilogue); staging per-thread work halves.
// R20's global_load_lds was neutral -> reg staging (R19 style) retained.

#define L2E 1.44269504088896340736f

#if defined(__has_builtin)
#  if __has_builtin(__builtin_amdgcn_exp2f)
#    define EXP2(x) __builtin_amdgcn_exp2f(x)
#  else
#    define EXP2(x) exp2f(x)
#  endif
#else
#  define EXP2(x) exp2f(x)
#endif

typedef __attribute__((ext_vector_type(8))) __bf16 bf16x8;
typedef __attribute__((ext_vector_type(4))) float f32x4;
typedef __attribute__((ext_vector_type(16))) float f32x16;

static __device__ __forceinline__ unsigned pk2(float a, float b) {
    union { unsigned u; __bf16 h[2]; } cv;
    cv.h[0] = (__bf16)a; cv.h[1] = (__bf16)b;
    return cv.u;
}

static __device__ __forceinline__ unsigned short f2bf(float f) {
    union { unsigned short s; __bf16 h; } cv;
    cv.h = (__bf16)f;
    return cv.s;
}

static __device__ __forceinline__ float bflo(unsigned u) {
    union { unsigned u; float f; } cv; cv.u = u << 16; return cv.f;
}
static __device__ __forceinline__ float bfhi(unsigned u) {
    union { unsigned u; float f; } cv; cv.u = u & 0xFFFF0000u; return cv.f;
}

// ---------------------------------------------------------------------------
// Kernel 0: QKV projection. 1D grid 768, XCD-swizzled decode (R18, proven):
//   c=g&7 (XCD), i=g>>3, x=i&3 (n-tile), p=(i>>2)*8+c, y=p&63, z=p>>6.
//   z=0 -> Qp[bh][s][d] scaled by L2E/8, z=1 -> Kp, z=2 -> Vt[bh][d][s].
// ---------------------------------------------------------------------------
__global__ __launch_bounds__(256) void qkv_kernel(
    const float* __restrict__ Xq, const float* __restrict__ Xk,
    const float* __restrict__ Xv, const float* __restrict__ W,
    const float* __restrict__ bias,
    unsigned short* __restrict__ Qp, unsigned short* __restrict__ Kp,
    unsigned short* __restrict__ Vt)
{
    __shared__ unsigned short lA[128][40];
    __shared__ unsigned short lB[128][40];

    const int g = blockIdx.x;
    const int c = g & 7, i = g >> 3;
    const int x = i & 3;
    const int p = (i >> 2) * 8 + c;     // panel 0..191
    const int y = p & 63;
    const int z = p >> 6;

    const float* X  = (z == 0) ? Xq : (z == 1) ? Xk : Xv;
    const float* Wz = W + (size_t)z * 512 * 512;
    const int rb = y * 128;
    const int nb = x * 128;
    const int tid  = threadIdx.x;
    const int lane = tid & 63, wave = tid >> 6;
    const int wr = wave >> 1, wc = wave & 1;
    const int lq = lane & 15, lg = lane >> 4;

    f32x4 acc[4][4];
#pragma unroll
    for (int ii = 0; ii < 4; ++ii)
#pragma unroll
        for (int j = 0; j < 4; ++j) acc[ii][j] = (f32x4){0.f, 0.f, 0.f, 0.f};

    const int srow = tid >> 1;
    const int scol = (tid & 1) * 16;

    for (int kt = 0; kt < 16; ++kt) {
        const int k0 = kt * 32;
        if (kt) __syncthreads();
        {
            const float* gp = X + (size_t)(rb + srow) * 512 + k0 + scol;
            float4 x0 = *(const float4*)(gp + 0);
            float4 x1 = *(const float4*)(gp + 4);
            float4 x2 = *(const float4*)(gp + 8);
            float4 x3 = *(const float4*)(gp + 12);
            uint4 w0, w1;
            w0.x = pk2(x0.x, x0.y); w0.y = pk2(x0.z, x0.w);
            w0.z = pk2(x1.x, x1.y); w0.w = pk2(x1.z, x1.w);
            w1.x = pk2(x2.x, x2.y); w1.y = pk2(x2.z, x2.w);
            w1.z = pk2(x3.x, x3.y); w1.w = pk2(x3.z, x3.w);
            *(uint4*)&lA[srow][scol] = w0;
            *(uint4*)&lA[srow][scol + 8] = w1;
        }
        {
            const float* gp = Wz + (size_t)(nb + srow) * 512 + k0 + scol;
            float4 x0 = *(const float4*)(gp + 0);
            float4 x1 = *(const float4*)(gp + 4);
            float4 x2 = *(const float4*)(gp + 8);
            float4 x3 = *(const float4*)(gp + 12);
            uint4 w0, w1;
            w0.x = pk2(x0.x, x0.y); w0.y = pk2(x0.z, x0.w);
            w0.z = pk2(x1.x, x1.y); w0.w = pk2(x1.z, x1.w);
            w1.x = pk2(x2.x, x2.y); w1.y = pk2(x2.z, x2.w);
            w1.z = pk2(x3.x, x3.y); w1.w = pk2(x3.z, x3.w);
            *(uint4*)&lB[srow][scol] = w0;
            *(uint4*)&lB[srow][scol + 8] = w1;
        }
        __syncthreads();

        bf16x8 af[4], bf[4];
#pragma unroll
        for (int mi = 0; mi < 4; ++mi)
            af[mi] = *(const bf16x8*)&lA[wr * 64 + mi * 16 + lq][lg * 8];
#pragma unroll
        for (int ni = 0; ni < 4; ++ni)
            bf[ni] = *(const bf16x8*)&lB[wc * 64 + ni * 16 + lq][lg * 8];
#pragma unroll
        for (int mi = 0; mi < 4; ++mi)
#pragma unroll
            for (int ni = 0; ni < 4; ++ni)
                acc[mi][ni] = __builtin_amdgcn_mfma_f32_16x16x32_bf16(
                    af[mi], bf[ni], acc[mi][ni], 0, 0, 0);
    }

    const float* bz = bias + z * 512;
#pragma unroll
    for (int ni = 0; ni < 4; ++ni) {
        const int n = nb + wc * 64 + ni * 16 + lq;
        const float bv = bz[n];
        const int h = n >> 6, d = n & 63;
#pragma unroll
        for (int mi = 0; mi < 4; ++mi) {
#pragma unroll
            for (int r = 0; r < 4; ++r) {
                const int t = rb + wr * 64 + mi * 16 + lg * 4 + r;
                float v = acc[mi][ni][r] + bv;
                const int s = t >> 2, b = t & 3;
                if (z == 0) {
                    v *= 0.125f * L2E;
                    Qp[((size_t)(b * 8 + h) * 2048 + s) * 64 + d] = f2bf(v);
                } else if (z == 1) {
                    Kp[((size_t)(b * 8 + h) * 2048 + s) * 64 + d] = f2bf(v);
                } else {
                    Vt[((size_t)(b * 8 + h) * 64 + d) * 2048 + s] = f2bf(v);
                }
            }
        }
    }
}

// ---------------------------------------------------------------------------
// Kernel 0.5: mask -> bf16 fragment layout via LDS transpose (R12 verbatim).
// Mf[(bq*64+kt)*1024 + lane*16 + jj] =
//   mask[b][qt*32+(lane&31)][kt*32 + (jj&3)+8*(jj>>2)+4*(lane>>5)] * L2E
// ---------------------------------------------------------------------------
__global__ __launch_bounds__(256) void maskprep_kernel(
    const float* __restrict__ mask, unsigned short* __restrict__ Mf)
{
    __shared__ float lT[32][261];
    const int tid = threadIdx.x;
    const int bq = blockIdx.y;                  // b*64 + qt
    const int kx = blockIdx.x;                  // k-chunk of 256
    const float* base = mask + ((size_t)(bq >> 6) * 2048 + (bq & 63) * 32) * 2048
                        + (size_t)kx * 256;

    const int r = tid >> 3, ci = tid & 7;
    const float* rp = base + (size_t)r * 2048;
#pragma unroll
    for (int j = 0; j < 8; ++j) {
        const int cidx = (ci + j * 8) * 4;
        float4 v = *(const float4*)(rp + cidx);
        lT[r][cidx + 0] = v.x * L2E;
        lT[r][cidx + 1] = v.y * L2E;
        lT[r][cidx + 2] = v.z * L2E;
        lT[r][cidx + 3] = v.w * L2E;
    }
    __syncthreads();

    const int w = tid >> 6, lane = tid & 63;
    const int lc = lane & 31, hi = lane >> 5;
#pragma unroll
    for (int t = 0; t < 2; ++t) {
        const int ktl = w * 2 + t;
        float pv[16];
#pragma unroll
        for (int jj = 0; jj < 16; ++jj)
            pv[jj] = lT[lc][ktl * 32 + (jj & 3) + 8 * (jj >> 2) + 4 * hi];
        unsigned short* dst = Mf + ((size_t)bq * 64 + kx * 8 + ktl) * 1024 + lane * 16;
        *(uint4*)(dst) = make_uint4(pk2(pv[0], pv[1]), pk2(pv[2], pv[3]),
                                    pk2(pv[4], pv[5]), pk2(pv[6], pv[7]));
        *(uint4*)(dst + 8) = make_uint4(pk2(pv[8], pv[9]),  pk2(pv[10], pv[11]),
                                        pk2(pv[12], pv[13]), pk2(pv[14], pv[15]));
    }
}

// ---------------------------------------------------------------------------
// Kernel 1: flash attention. grid (8 q-tiles of 256, 32 bh), 512 thr/8 waves.
// Wave w handles q rows qb + w*32 .. +31; all waves share one K/V LDS stream
// (K/V traffic halves vs 128-q blocks). 32x32x16 MFMA, swapped QK^T, mask
// C-init from Mf, EXP2 hw intrinsic, dbuf LDS + XOR swizzle, 1 barrier/tile.
// ---------------------------------------------------------------------------
#define SWAP32(a, b) asm("v_permlane32_swap_b32 %0, %1" : "+v"(a), "+v"(b))

#define COMPUTE(KC, VC, M) do {                                                \
    bf16x8 pf[4];                                                              \
    _Pragma("unroll")                                                          \
    for (int kblk = 0; kblk < 2; ++kblk) {                                     \
        f32x16 z;                                                              \
        {                                                                      \
            const uint4 m0 = M[kblk][0], m1 = M[kblk][1];                      \
            z[0]  = bflo(m0.x); z[1]  = bfhi(m0.x);                            \
            z[2]  = bflo(m0.y); z[3]  = bfhi(m0.y);                            \
            z[4]  = bflo(m0.z); z[5]  = bfhi(m0.z);                            \
            z[6]  = bflo(m0.w); z[7]  = bfhi(m0.w);                            \
            z[8]  = bflo(m1.x); z[9]  = bfhi(m1.x);                            \
            z[10] = bflo(m1.y); z[11] = bfhi(m1.y);                            \
            z[12] = bflo(m1.z); z[13] = bfhi(m1.z);                            \
            z[14] = bflo(m1.w); z[15] = bfhi(m1.w);                            \
        }                                                                      \
        __builtin_amdgcn_s_setprio(1);                                         \
        _Pragma("unroll")                                                      \
        for (int s = 0; s < 4; ++s) {                                          \
            bf16x8 kf = *(const bf16x8*)((KC) + fof[kblk][s]);                 \
            z = __builtin_amdgcn_mfma_f32_32x32x16_bf16(kf, qf[s], z, 0,0,0);  \
        }                                                                      \
        __builtin_amdgcn_s_setprio(0);                                         \
        float p[16];                                                           \
        _Pragma("unroll")                                                      \
        for (int ii = 0; ii < 16; ++ii) p[ii] = EXP2(z[ii]);                   \
        lsum += (((p[0]+p[1])+(p[2]+p[3])) + ((p[4]+p[5])+(p[6]+p[7])))        \
              + (((p[8]+p[9])+(p[10]+p[11])) + ((p[12]+p[13])+(p[14]+p[15]))); \
        unsigned a0 = pk2(p[0], p[1]),   b0 = pk2(p[4], p[5]);                 \
        unsigned a1 = pk2(p[2], p[3]),   b1 = pk2(p[6], p[7]);                 \
        SWAP32(a0, b0); SWAP32(a1, b1);                                        \
        union { unsigned w[4]; bf16x8 v; } u0;                                 \
        u0.w[0] = a0; u0.w[1] = a1; u0.w[2] = b0; u0.w[3] = b1;                \
        pf[kblk*2] = u0.v;                                                     \
        unsigned c0 = pk2(p[8], p[9]),   d0 = pk2(p[12], p[13]);               \
        unsigned c1 = pk2(p[10], p[11]), d1 = pk2(p[14], p[15]);               \
        SWAP32(c0, d0); SWAP32(c1, d1);                                        \
        union { unsigned w[4]; bf16x8 v; } u1;                                 \
        u1.w[0] = c0; u1.w[1] = c1; u1.w[2] = d0; u1.w[3] = d1;                \
        pf[kblk*2+1] = u1.v;                                                   \
    }                                                                          \
    __builtin_amdgcn_s_setprio(1);                                             \
    _Pragma("unroll")                                                          \
    for (int s = 0; s < 4; ++s) {                                              \
        bf16x8 vf0 = *(const bf16x8*)((VC) + fof[0][s]);                       \
        o0 = __builtin_amdgcn_mfma_f32_32x32x16_bf16(vf0, pf[s], o0, 0,0,0);   \
        bf16x8 vf1 = *(const bf16x8*)((VC) + fof[1][s]);                       \
        o1 = __builtin_amdgcn_mfma_f32_32x32x16_bf16(vf1, pf[s], o1, 0,0,0);   \
    }                                                                          \
    __builtin_amdgcn_s_setprio(0);                                             \
} while (0)

#define LOADNEXT(MD) do {                                                      \
    ka = *(const uint4*)(pgK);                                                 \
    va = *(const uint4*)(pgV);                                                 \
    MD[0][0] = *(const uint4*)(pmf);                                           \
    MD[0][1] = *(const uint4*)(pmf + 8);                                       \
    MD[1][0] = *(const uint4*)(pmf + 1024);                                    \
    MD[1][1] = *(const uint4*)(pmf + 1032);                                    \
    pgK += 4096; pgV += 64; pmf += 2048;                                       \
} while (0)

#define STORE(BUF) do {                                                        \
    *(uint4*)&lK[BUF][srow][su * 8] = ka;                                      \
    *(uint4*)&lV[BUF][srow][su * 8] = va;                                      \
} while (0)

__global__ __launch_bounds__(512, 2) void attn_kernel(
    const unsigned short* __restrict__ Qp, const unsigned short* __restrict__ Kp,
    const unsigned short* __restrict__ Vt, const unsigned short* __restrict__ Mf,
    unsigned short* __restrict__ AO)
{
    __shared__ unsigned short lK[2][64][64];   // [buf][k][d], swizzled 16B units
    __shared__ unsigned short lV[2][64][64];   // [buf][d][k], same swizzle

    const int bh = blockIdx.y;
    const int b = bh >> 3, h = bh & 7;
    const int qb = blockIdx.x * 256;
    const int tid  = threadIdx.x;
    const int lane = tid & 63, wave = tid >> 6;     // wave 0..7
    const int lc = lane & 31, hi = lane >> 5;
    const int qg = qb + wave * 32 + lc;

    bf16x8 qf[4];
    {
        const unsigned short* qp = Qp + ((size_t)bh * 2048 + qg) * 64 + hi * 8;
#pragma unroll
        for (int s = 0; s < 4; ++s)
            qf[s] = *(const bf16x8*)(qp + s * 16);
    }

    f32x16 o0, o1;
#pragma unroll
    for (int ii = 0; ii < 16; ++ii) { o0[ii] = 0.f; o1[ii] = 0.f; }
    float lsum = 0.f;

    int fof[2][4];
#pragma unroll
    for (int blk = 0; blk < 2; ++blk)
#pragma unroll
        for (int s = 0; s < 4; ++s)
            fof[blk][s] = (blk * 32 + lc) * 128 +
                          ((((s << 1) | hi) ^ (lane & 7)) * 16);

    const char* lK0c = (const char*)&lK[0][0][0];
    const char* lK1c = (const char*)&lK[1][0][0];
    const char* lV0c = (const char*)&lV[0][0][0];
    const char* lV1c = (const char*)&lV[1][0][0];

    // staging: 512 threads, one 16B unit each for K and V.
    // thread -> row tid>>3 (0..63), unit tid&7; XOR swizzle unit^(row&7).
    const int srow = tid >> 3;
    const int scu  = tid & 7;
    const int su   = scu ^ (srow & 7);
    const unsigned short* pgK = Kp + (size_t)bh * 131072 + (size_t)srow * 64 + scu * 8;
    const unsigned short* pgV = Vt + (size_t)bh * 131072 + (size_t)srow * 2048 + scu * 8;
    // wave's q-subtile index: qb/32 + wave = blockIdx.x*8 + wave
    const unsigned short* pmf = Mf +
        ((size_t)(b * 64 + blockIdx.x * 8 + wave) * 64) * 1024 + lane * 16;

    uint4 ka, va;
    uint4 mA[2][2], mB[2][2];

    LOADNEXT(mA);
    STORE(0);
    __syncthreads();

    for (int kb2 = 0; kb2 < 16; ++kb2) {
        // even half: prefetch tile -> LDS[1], compute LDS[0]/mA
        {
            LOADNEXT(mB);
            COMPUTE(lK0c, lV0c, mA);
            STORE(1);
            __syncthreads();
        }
        // odd half: prefetch tile -> LDS[0] (if any), compute LDS[1]/mB
        {
            if (kb2 < 15) LOADNEXT(mA);
            COMPUTE(lK1c, lV1c, mB);
            if (kb2 < 15) {
                STORE(0);
                __syncthreads();
            }
        }
    }

    // halves (lane, lane^32) hold disjoint k partials for q=lc
    lsum += __shfl_xor(lsum, 32);
    const float inv = 1.0f / lsum;

    unsigned short* ao = AO + ((size_t)qg * 4 + b) * 512 + h * 64;
#pragma unroll
    for (int gq = 0; gq < 4; ++gq) {
        const int d0 = gq * 8 + hi * 4;
        *(uint2*)(ao + d0) =
            make_uint2(pk2(o0[4*gq+0] * inv, o0[4*gq+1] * inv),
                       pk2(o0[4*gq+2] * inv, o0[4*gq+3] * inv));
        *(uint2*)(ao + 32 + d0) =
            make_uint2(pk2(o1[4*gq+0] * inv, o1[4*gq+1] * inv),
                       pk2(o1[4*gq+2] * inv, o1[4*gq+3] * inv));
    }
}

// ---------------------------------------------------------------------------
// Kernel 2: output projection. 1D grid 256, XCD-swizzled (R18):
//   c=g&7, i=g>>3, x=i&3 (n-tile), y=(i>>2)*8+c (m-tile 0..63).
// ---------------------------------------------------------------------------
__global__ __launch_bounds__(256) void oproj_kernel(
    const unsigned short* __restrict__ A, const float* __restrict__ W,
    const float* __restrict__ bias, float* __restrict__ out)
{
    __shared__ unsigned short lA[128][40];
    __shared__ unsigned short lB[128][40];

    const int g = blockIdx.x;
    const int c = g & 7, i = g >> 3;
    const int rb = ((i >> 2) * 8 + c) * 128;
    const int nb = (i & 3) * 128;
    const int tid  = threadIdx.x;
    const int lane = tid & 63, wave = tid >> 6;
    const int wr = wave >> 1, wc = wave & 1;
    const int lq = lane & 15, lg = lane >> 4;

    f32x4 acc[4][4];
#pragma unroll
    for (int ii = 0; ii < 4; ++ii)
#pragma unroll
        for (int j = 0; j < 4; ++j) acc[ii][j] = (f32x4){0.f, 0.f, 0.f, 0.f};

    const int srow = tid >> 1;
    const int scol = (tid & 1) * 16;

    for (int kt = 0; kt < 16; ++kt) {
        const int k0 = kt * 32;
        if (kt) __syncthreads();
        {
            const unsigned short* gp = A + (size_t)(rb + srow) * 512 + k0 + scol;
            *(uint4*)&lA[srow][scol]     = *(const uint4*)gp;
            *(uint4*)&lA[srow][scol + 8] = *(const uint4*)(gp + 8);
        }
        {
            const float* gp = W + (size_t)(nb + srow) * 512 + k0 + scol;
            float4 x0 = *(const float4*)(gp + 0);
            float4 x1 = *(const float4*)(gp + 4);
            float4 x2 = *(const float4*)(gp + 8);
            float4 x3 = *(const float4*)(gp + 12);
            uint4 w0, w1;
            w0.x = pk2(x0.x, x0.y); w0.y = pk2(x0.z, x0.w);
            w0.z = pk2(x1.x, x1.y); w0.w = pk2(x1.z, x1.w);
            w1.x = pk2(x2.x, x2.y); w1.y = pk2(x2.z, x2.w);
            w1.z = pk2(x3.x, x3.y); w1.w = pk2(x3.z, x3.w);
            *(uint4*)&lB[srow][scol] = w0;
            *(uint4*)&lB[srow][scol + 8] = w1;
        }
        __syncthreads();

        bf16x8 af[4], bfr[4];
#pragma unroll
        for (int mi = 0; mi < 4; ++mi)
            af[mi] = *(const bf16x8*)&lA[wr * 64 + mi * 16 + lq][lg * 8];
#pragma unroll
        for (int ni = 0; ni < 4; ++ni)
            bfr[ni] = *(const bf16x8*)&lB[wc * 64 + ni * 16 + lq][lg * 8];
#pragma unroll
        for (int mi = 0; mi < 4; ++mi)
#pragma unroll
            for (int ni = 0; ni < 4; ++ni)
                acc[mi][ni] = __builtin_amdgcn_mfma_f32_16x16x32_bf16(
                    af[mi], bfr[ni], acc[mi][ni], 0, 0, 0);
    }

#pragma unroll
    for (int ni = 0; ni < 4; ++ni) {
        const int n = nb + wc * 64 + ni * 16 + lq;
        const float bv = bias[n];
#pragma unroll
        for (int mi = 0; mi < 4; ++mi) {
#pragma unroll
            for (int r = 0; r < 4; ++r) {
                const int t = rb + wr * 64 + mi * 16 + lg * 4 + r;
                out[(size_t)t * 512 + n] = acc[mi][ni][r] + bv;
            }
        }
    }
}

extern "C" void kernel_launch(void* const* d_in, const int* in_sizes, int n_in,
                              void* d_out, int out_size, void* d_ws, size_t ws_size,
                              hipStream_t stream)
{
    (void)in_sizes; (void)n_in; (void)out_size; (void)ws_size;
    const float* query = (const float*)d_in[0];
    const float* key   = (const float*)d_in[1];
    const float* value = (const float*)d_in[2];
    const float* mask  = (const float*)d_in[3];
    const float* w_in  = (const float*)d_in[4];
    const float* b_in  = (const float*)d_in[5];
    const float* w_out = (const float*)d_in[6];
    const float* b_out = (const float*)d_in[7];
    float* out = (float*)d_out;

    char* ws = (char*)d_ws;
    const size_t MB = 1024 * 1024;
    unsigned short* Qp = (unsigned short*)(ws);            // [32][2048][64] bf16, 8 MB
    unsigned short* Kp = (unsigned short*)(ws + 8 * MB);   // 8 MB
    unsigned short* Vt = (unsigned short*)(ws + 16 * MB);  // [32][64][2048], 8 MB
    unsigned short* AO = (unsigned short*)(ws + 24 * MB);  // [8192][512] bf16, 8 MB
    unsigned short* Mf = (unsigned short*)(ws + 32 * MB);  // mask fragments, 32 MB

    qkv_kernel<<<dim3(768), 256, 0, stream>>>(query, key, value, w_in, b_in,
                                              Qp, Kp, Vt);
    maskprep_kernel<<<dim3(8, 256), 256, 0, stream>>>(mask, Mf);
    attn_kernel<<<dim3(8, 32), 512, 0, stream>>>(Qp, Kp, Vt, Mf, AO);
    oproj_kernel<<<dim3(256), 256, 0, stream>>>(AO, w_out, b_out, out);
}